// Round 4
// baseline (144.284 us; speedup 1.0000x reference)
//
#include <hip/hip_runtime.h>
#include <stdint.h>

typedef _Float16 half8 __attribute__((ext_vector_type(8)));
typedef float floatx4 __attribute__((ext_vector_type(4)));
typedef float floatx2 __attribute__((ext_vector_type(2)));

// ---------------------------------------------------------------------------
// Threefry-2x32, 20 rounds (JAX-compatible, partitionable variant)
// rotl forced to v_alignbit_b32 via builtin (guaranteed 1 instr/rotate).
// RNG BIT SCHEME IS VALIDATED — DO NOT TOUCH (bits = o0^o1 of (0, idx)).
// ---------------------------------------------------------------------------
__device__ __forceinline__ uint32_t rotl32(uint32_t v, int r) {
  return __builtin_amdgcn_alignbit(v, v, 32 - r);  // (v:v)>>(32-r) == rotl
}

__device__ __forceinline__ void threefry2x32(uint32_t k0, uint32_t k1,
                                             uint32_t x0, uint32_t x1,
                                             uint32_t& o0, uint32_t& o1) {
  uint32_t k2 = k0 ^ k1 ^ 0x1BD11BDAu;
  x0 += k0; x1 += k1;
#define TF_R(r) { x0 += x1; x1 = rotl32(x1, (r)); x1 ^= x0; }
  TF_R(13) TF_R(15) TF_R(26) TF_R(6)   x0 += k1; x1 += k2 + 1u;
  TF_R(17) TF_R(29) TF_R(16) TF_R(24)  x0 += k2; x1 += k0 + 2u;
  TF_R(13) TF_R(15) TF_R(26) TF_R(6)   x0 += k0; x1 += k1 + 3u;
  TF_R(17) TF_R(29) TF_R(16) TF_R(24)  x0 += k1; x1 += k2 + 4u;
  TF_R(13) TF_R(15) TF_R(26) TF_R(6)   x0 += k2; x1 += k0 + 5u;
#undef TF_R
  o0 = x0; o1 = x1;
}

// Tail of erfinv (w >= 5, ~0.34% of elements): full 9-coef Giles poly.
__device__ __forceinline__ float tail_p(float l2) {
  float w = l2 * -0.69314718f;
  float s = sqrtf(w) - 3.0f;
  float p = -0.000200214257f;
  p = fmaf(p, s, 0.000100950558f);
  p = fmaf(p, s, 0.00134934322f);
  p = fmaf(p, s, -0.00367342844f);
  p = fmaf(p, s, 0.00573950773f);
  p = fmaf(p, s, -0.0076224613f);
  p = fmaf(p, s, 0.00943887047f);
  p = fmaf(p, s, 1.00167406f);
  p = fmaf(p, s, 2.83297682f);
  return p;
}

// ---------------------------------------------------------------------------
// Paired noise multipliers nm = 1 + 0.01*sqrt(2)*erfinv(u) for (idx0, idx1).
// R4 changes vs validated R2/R3 scalar version:
//  - two elements packed as float2 -> v_pk_*_f32 on the f32 chain (threefry
//    stays scalar u32; the two interleaved chains also feed ILP).
//  - central poly 5 -> 3 coefs. Worst dropped-term error where |u| is large
//    (a -> +2.5): |dp| ~ 0.011 on erfinv -> ~1.6e-4 relative on val ->
//    ~2e-5 absolute on output (budget 4.9e-4, f16-matmul-dominated).
//  - tail branch (w >= 5) recomputes with the full 9-coef poly (rare).
// NOTE (NaN post-mortem, still applies): clamp u > -1 is REQUIRED; all-zero
// mantissa bits give u = -1 -> log(0) -> -inf -> NaN through the norm.
// ---------------------------------------------------------------------------
__device__ __forceinline__ floatx2 noise_pair(uint32_t ka0, uint32_t ka1,
                                              uint32_t idx0, uint32_t idx1) {
  uint32_t a0, a1, b0, b1;
  threefry2x32(ka0, ka1, 0u, idx0, a0, a1);
  threefry2x32(ka0, ka1, 0u, idx1, b0, b1);
  const uint32_t bitsA = a0 ^ a1, bitsB = b0 ^ b1;
  floatx2 vf;
  vf.x = __uint_as_float(__builtin_amdgcn_alignbit(0x7Fu, bitsA, 9));  // [1,2)
  vf.y = __uint_as_float(__builtin_amdgcn_alignbit(0x7Fu, bitsB, 9));
  floatx2 u = __builtin_elementwise_fma(vf, (floatx2){2.0f, 2.0f},
                                        (floatx2){-3.0f, -3.0f});
  u = __builtin_elementwise_max(u, (floatx2){-0.99999994f, -0.99999994f});
  floatx2 t = __builtin_elementwise_fma(-u, u, (floatx2){1.0f, 1.0f});
  floatx2 l2;
  l2.x = __log2f(t.x);
  l2.y = __log2f(t.y);
  floatx2 a = __builtin_elementwise_fma(
      l2, (floatx2){-0.69314718f, -0.69314718f}, (floatx2){-2.5f, -2.5f});
  floatx2 p = __builtin_elementwise_fma(
      (floatx2){-0.00417768164f, -0.00417768164f}, a,
      (floatx2){0.246640727f, 0.246640727f});
  p = __builtin_elementwise_fma(p, a, (floatx2){1.50140941f, 1.50140941f});
  if (__builtin_expect(l2.x <= -7.2134752f, 0)) p.x = tail_p(l2.x);
  if (__builtin_expect(l2.y <= -7.2134752f, 0)) p.y = tail_p(l2.y);
  floatx2 uc = u * (floatx2){0.014142135623730951f, 0.014142135623730951f};
  return __builtin_elementwise_fma(p, uc, (floatx2){1.0f, 1.0f});
}

// ---------------------------------------------------------------------------
// Device globals: precomputed per-(rowtile,lane) A fragments (f16) + noise key
// g_afrag[t][16], t = rowtile*64+lane: halfs 0..7 = af0 (k=0..31), 8..15 = af1
// ---------------------------------------------------------------------------
__device__ __align__(16) _Float16 g_afrag[256 * 16];
__device__ uint32_t g_key[2];

// ---------------------------------------------------------------------------
// Setup: fold 3 rotations into one real 64-pt circulant kernel g[64] (fp32,
// double only for twiddles), then emit per-tid MFMA A-fragments + threefry key.
// (validated: A[row][k] = g[(row-k)&63] — convolution, not correlation)
// ---------------------------------------------------------------------------
__global__ void setup_kernel(const float* __restrict__ rx,
                             const float* __restrict__ ry,
                             const float* __restrict__ rz) {
  __shared__ float cre[3][64], cim[3][64];
  __shared__ float Gr[64], Gi[64];
  __shared__ float twc[64], tws[64];
  __shared__ float gs[64];
  const int t = threadIdx.x;  // 256 threads

  if (t < 32) {
    const float* ps[3] = {rx, ry, rz};
    for (int a = 0; a < 3; ++a) {
      float s = 0.0f;
      for (int r = 0; r < 16; ++r) s += ps[a][t * 16 + r];
      float h = 0.5f * s;  // theta[:32] * 0.5
      float ch = cosf(h), sh = sinf(h);
      if (a < 2) {  // rx, ry: repeat(cos(half), 2) -> real diag
        cre[a][2 * t] = ch;     cim[a][2 * t] = 0.0f;
        cre[a][2 * t + 1] = ch; cim[a][2 * t + 1] = 0.0f;
      } else {      // rz: [exp(-ih), exp(+ih)] interleaved
        cre[2][2 * t] = ch;     cim[2][2 * t] = -sh;
        cre[2][2 * t + 1] = ch; cim[2][2 * t + 1] = sh;
      }
    }
  }
  if (t < 64) {
    double ang = (2.0 * 3.14159265358979323846 / 64.0) * (double)t;
    twc[t] = (float)cos(ang);
    tws[t] = (float)sin(ang);
  }
  __syncthreads();

  if (t < 64) {  // Hermitian-symmetrize each spectrum, complex product
    const int k = t, kn = (64 - k) & 63;
    float pr = 1.0f, pi = 0.0f;
    for (int a = 0; a < 3; ++a) {
      float cr = 0.5f * (cre[a][k] + cre[a][kn]);
      float ci = 0.5f * (cim[a][k] - cim[a][kn]);
      float nr = pr * cr - pi * ci;
      float ni = pr * ci + pi * cr;
      pr = nr; pi = ni;
    }
    Gr[k] = pr; Gi[k] = pi;
  }
  __syncthreads();

  if (t < 64) {  // g[m] = Re( ifft(G)[m] )
    const int mi = t;
    float s = 0.0f;
    for (int k = 0; k < 64; ++k) {
      int idx = (k * mi) & 63;
      s = fmaf(Gr[k], twc[idx], s);
      s = fmaf(-Gi[k], tws[idx], s);
    }
    gs[mi] = s * (1.0f / 64.0f);
  }
  __syncthreads();

  {
    const int w = t >> 6, lane = t & 63, quad = lane >> 4, m = lane & 15;
    const int r0 = 16 * w + m - 8 * quad;
#pragma unroll
    for (int j = 0; j < 8; ++j) {
      g_afrag[t * 16 + j]     = (_Float16)gs[(r0 - j) & 63];
      g_afrag[t * 16 + 8 + j] = (_Float16)gs[(r0 - 32 - j) & 63];
    }
  }

  if (t == 0) {
    uint32_t o0, o1;
    threefry2x32(0u, 42u, 0u, 0u, o0, o1);  // ka = split(key(42))[0]
    g_key[0] = o0; g_key[1] = o1;
  }
}

// ---------------------------------------------------------------------------
// R4: WITHIN-ROUND A/B DISCRIMINATOR. R3 raised occupancy 55->65% with zero
// duration change -> simple TLP-latency theory falsified. Remaining split:
//   H_A: VALU pipe truly ~85% busy  -> only instruction cuts help.
//   H_L: per-block phase serialization (load|MFMA|RNG|reduce|store) exposed
//        -> moving RNG under the in-flight loads helps (R1 retried WITHOUT
//        the spill: at the 64-reg baseline, +16 live regs fits (512,6)=84).
// qmainA (rows 0..2047):    R3 ordering, slim pk math.
// qmainB (rows 2048..4095): RNG before barrier, slim pk math.
// Read: durB/durA ~1.0 => H_A; <=0.85 => H_L. WRITE_SIZE per dispatch must
// stay exactly 32768 KB (growth = spill, esp. B).
// ---------------------------------------------------------------------------
__global__ __launch_bounds__(512, 6) void qmainA(const float* __restrict__ x,
                                                 float* __restrict__ out) {
  __shared__ __align__(16) _Float16 Xt[64 * 72];  // [d][q], row stride 72 halfs
  __shared__ float red[8];
  const int tid = threadIdx.x;   // 0..511
  const int row = blockIdx.x;    // rows 0..2047
  const int lane = tid & 63;
  const int w = tid >> 6;        // wave id 0..7
  const int wr = w & 3;          // output row tile: q rows 16wr..16wr+15
  const int wc = w >> 2;         // output col half: d cols 32wc..32wc+31
  const int quad = lane >> 4;    // 0..3
  const int m = lane & 15;       // A's m index == D's col index

  const half8* at = (const half8*)g_afrag;
  const int ai = (wr << 6) | lane;
  half8 af0 = at[2 * ai];
  half8 af1 = at[2 * ai + 1];
  const uint32_t ka0 = g_key[0], ka1 = g_key[1];

  // stage row -> Xt (cvt f16 + transpose in registers); v[4] dies here
  {
    const float* xr = x + (size_t)row * 4096;
    const int d0 = (tid & 31) * 2;
    const int q0 = (tid >> 5) * 4;
    float2 v[4];
#pragma unroll
    for (int s = 0; s < 4; ++s) v[s] = *(const float2*)(xr + (q0 + s) * 64 + d0);
    union { _Float16 h[4]; uint2 u; } r0, r1;
#pragma unroll
    for (int s = 0; s < 4; ++s) { r0.h[s] = (_Float16)v[s].x; r1.h[s] = (_Float16)v[s].y; }
    *(uint2*)&Xt[d0 * 72 + q0] = r0.u;
    *(uint2*)&Xt[(d0 + 1) * 72 + q0] = r1.u;
  }
  __syncthreads();

  // 4 MFMAs: acc[cc] covers Y[16wr+4quad+r][16*(2wc+cc)+m]
  floatx4 acc[2];
#pragma unroll
  for (int cc = 0; cc < 2; ++cc) {
    const int c = 2 * wc + cc;
    const _Float16* bp = &Xt[(16 * c + m) * 72 + 8 * quad];
    half8 b0 = *(const half8*)bp;
    half8 b1 = *(const half8*)(bp + 32);
    acc[cc] = (floatx4){0.0f, 0.0f, 0.0f, 0.0f};
    acc[cc] = __builtin_amdgcn_mfma_f32_16x16x32_f16(af0, b0, acc[cc], 0, 0, 0);
    acc[cc] = __builtin_amdgcn_mfma_f32_16x16x32_f16(af1, b1, acc[cc], 0, 0, 0);
  }

  // fused noise (paired cc=0,1) + apply in place + sum of squares
  const uint32_t idxbase = ((uint32_t)row << 12) +
                           (uint32_t)(((16 * wr + 4 * quad) << 6) + (wc << 5) + m);
  floatx2 ss = {0.0f, 0.0f};
#pragma unroll
  for (int r = 0; r < 4; ++r) {
    const uint32_t i0 = idxbase + (uint32_t)(r * 64);
    floatx2 nm = noise_pair(ka0, ka1, i0, i0 + 16u);
    floatx2 val = nm * (floatx2){acc[0][r], acc[1][r]};
    acc[0][r] = val.x; acc[1][r] = val.y;
    ss = __builtin_elementwise_fma(val, val, ss);
  }
  float ssum = ss.x + ss.y;

#pragma unroll
  for (int off = 32; off >= 1; off >>= 1) ssum += __shfl_xor(ssum, off, 64);
  if (lane == 0) red[w] = ssum;
  __syncthreads();
  float total = 0.0f;
#pragma unroll
  for (int i = 0; i < 8; ++i) total += red[i];
  const float scale = 1.0f / (sqrtf(total) + 1e-8f);

  float* ob = out + (size_t)row * 4096 +
              (size_t)(((16 * wr + 4 * quad) << 6) + (wc << 5) + m);
#pragma unroll
  for (int cc = 0; cc < 2; ++cc)
#pragma unroll
    for (int r = 0; r < 4; ++r)
      ob[r * 64 + 16 * cc] = fabsf(acc[cc][r]) * scale;
}

__global__ __launch_bounds__(512, 6) void qmainB(const float* __restrict__ x,
                                                 float* __restrict__ out) {
  __shared__ __align__(16) _Float16 Xt[64 * 72];
  __shared__ float red[8];
  const int tid = threadIdx.x;
  const int row = 2048 + blockIdx.x;  // rows 2048..4095
  const int lane = tid & 63;
  const int w = tid >> 6;
  const int wr = w & 3;
  const int wc = w >> 2;
  const int quad = lane >> 4;
  const int m = lane & 15;

  // phase 0: issue global loads (x row + A fragments), keep in flight
  const float* xr = x + (size_t)row * 4096;
  const int d0 = (tid & 31) * 2;
  const int q0 = (tid >> 5) * 4;
  float2 v[4];
#pragma unroll
  for (int s = 0; s < 4; ++s) v[s] = *(const float2*)(xr + (q0 + s) * 64 + d0);
  const half8* at = (const half8*)g_afrag;
  const int ai = (wr << 6) | lane;
  half8 af0 = at[2 * ai];
  half8 af1 = at[2 * ai + 1];
  const uint32_t ka0 = g_key[0], ka1 = g_key[1];

  // phase 1: ALL noise multipliers while loads are in flight (data-indep RNG)
  const uint32_t idxbase = ((uint32_t)row << 12) +
                           (uint32_t)(((16 * wr + 4 * quad) << 6) + (wc << 5) + m);
  floatx2 nm[4];
#pragma unroll
  for (int r = 0; r < 4; ++r) {
    const uint32_t i0 = idxbase + (uint32_t)(r * 64);
    nm[r] = noise_pair(ka0, ka1, i0, i0 + 16u);
  }

  // phase 2: cvt + transposed LDS staging (loads completed under phase 1)
  {
    union { _Float16 h[4]; uint2 u; } r0, r1;
#pragma unroll
    for (int s = 0; s < 4; ++s) { r0.h[s] = (_Float16)v[s].x; r1.h[s] = (_Float16)v[s].y; }
    *(uint2*)&Xt[d0 * 72 + q0] = r0.u;
    *(uint2*)&Xt[(d0 + 1) * 72 + q0] = r1.u;
  }
  __syncthreads();

  floatx4 acc[2];
#pragma unroll
  for (int cc = 0; cc < 2; ++cc) {
    const int c = 2 * wc + cc;
    const _Float16* bp = &Xt[(16 * c + m) * 72 + 8 * quad];
    half8 b0 = *(const half8*)bp;
    half8 b1 = *(const half8*)(bp + 32);
    acc[cc] = (floatx4){0.0f, 0.0f, 0.0f, 0.0f};
    acc[cc] = __builtin_amdgcn_mfma_f32_16x16x32_f16(af0, b0, acc[cc], 0, 0, 0);
    acc[cc] = __builtin_amdgcn_mfma_f32_16x16x32_f16(af1, b1, acc[cc], 0, 0, 0);
  }

  // apply precomputed noise + sum of squares
  floatx2 ss = {0.0f, 0.0f};
#pragma unroll
  for (int r = 0; r < 4; ++r) {
    floatx2 val = nm[r] * (floatx2){acc[0][r], acc[1][r]};
    acc[0][r] = val.x; acc[1][r] = val.y;
    ss = __builtin_elementwise_fma(val, val, ss);
  }
  float ssum = ss.x + ss.y;

#pragma unroll
  for (int off = 32; off >= 1; off >>= 1) ssum += __shfl_xor(ssum, off, 64);
  if (lane == 0) red[w] = ssum;
  __syncthreads();
  float total = 0.0f;
#pragma unroll
  for (int i = 0; i < 8; ++i) total += red[i];
  const float scale = 1.0f / (sqrtf(total) + 1e-8f);

  float* ob = out + (size_t)row * 4096 +
              (size_t)(((16 * wr + 4 * quad) << 6) + (wc << 5) + m);
#pragma unroll
  for (int cc = 0; cc < 2; ++cc)
#pragma unroll
    for (int r = 0; r < 4; ++r)
      ob[r * 64 + 16 * cc] = fabsf(acc[cc][r]) * scale;
}

// ---------------------------------------------------------------------------
extern "C" void kernel_launch(void* const* d_in, const int* in_sizes, int n_in,
                              void* d_out, int out_size, void* d_ws, size_t ws_size,
                              hipStream_t stream) {
  const float* x  = (const float*)d_in[0];
  const float* rx = (const float*)d_in[1];
  const float* ry = (const float*)d_in[2];
  const float* rz = (const float*)d_in[3];
  float* out = (float*)d_out;

  setup_kernel<<<1, 256, 0, stream>>>(rx, ry, rz);
  qmainA<<<2048, 512, 0, stream>>>(x, out);  // rows 0..2047
  qmainB<<<2048, 512, 0, stream>>>(x, out);  // rows 2048..4095
}

// Round 5
// 138.720 us; speedup vs baseline: 1.0401x; 1.0401x over previous
//
#include <hip/hip_runtime.h>
#include <stdint.h>

typedef _Float16 half8 __attribute__((ext_vector_type(8)));
typedef float floatx4 __attribute__((ext_vector_type(4)));
typedef float floatx2 __attribute__((ext_vector_type(2)));

// ---------------------------------------------------------------------------
// Threefry-2x32, 20 rounds (JAX-compatible, partitionable variant)
// rotl forced to v_alignbit_b32 via builtin (guaranteed 1 instr/rotate).
// RNG BIT SCHEME IS VALIDATED — DO NOT TOUCH (bits = o0^o1 of (0, idx)).
// ---------------------------------------------------------------------------
__device__ __forceinline__ uint32_t rotl32(uint32_t v, int r) {
  return __builtin_amdgcn_alignbit(v, v, 32 - r);  // (v:v)>>(32-r) == rotl
}

__device__ __forceinline__ void threefry2x32(uint32_t k0, uint32_t k1,
                                             uint32_t x0, uint32_t x1,
                                             uint32_t& o0, uint32_t& o1) {
  uint32_t k2 = k0 ^ k1 ^ 0x1BD11BDAu;
  x0 += k0; x1 += k1;
#define TF_R(r) { x0 += x1; x1 = rotl32(x1, (r)); x1 ^= x0; }
  TF_R(13) TF_R(15) TF_R(26) TF_R(6)   x0 += k1; x1 += k2 + 1u;
  TF_R(17) TF_R(29) TF_R(16) TF_R(24)  x0 += k2; x1 += k0 + 2u;
  TF_R(13) TF_R(15) TF_R(26) TF_R(6)   x0 += k0; x1 += k1 + 3u;
  TF_R(17) TF_R(29) TF_R(16) TF_R(24)  x0 += k1; x1 += k2 + 4u;
  TF_R(13) TF_R(15) TF_R(26) TF_R(6)   x0 += k2; x1 += k0 + 5u;
#undef TF_R
  o0 = x0; o1 = x1;
}

// Tail of erfinv (w >= 5, ~0.34% of elements): full 9-coef Giles poly.
__device__ __forceinline__ float tail_p(float l2) {
  float w = l2 * -0.69314718f;
  float s = sqrtf(w) - 3.0f;
  float p = -0.000200214257f;
  p = fmaf(p, s, 0.000100950558f);
  p = fmaf(p, s, 0.00134934322f);
  p = fmaf(p, s, -0.00367342844f);
  p = fmaf(p, s, 0.00573950773f);
  p = fmaf(p, s, -0.0076224613f);
  p = fmaf(p, s, 0.00943887047f);
  p = fmaf(p, s, 1.00167406f);
  p = fmaf(p, s, 2.83297682f);
  return p;
}

// ---------------------------------------------------------------------------
// Paired noise multipliers nm = 1 + 0.01*sqrt(2)*erfinv(u) for (idx0, idx1).
// Harness-validated in R4 at absmax 4.88e-4 (identical to scalar R2/R3):
//  - two elements packed as float2 -> v_pk_*_f32 on the f32 chain (threefry
//    stays scalar u32; the two interleaved chains also feed ILP).
//  - central poly 3 coefs; dropped-term err ~0.011 on erfinv -> ~2e-5 on
//    output (budget 4.9e-4, f16-matmul-dominated).
//  - tail branch (w >= 5) recomputes with the full 9-coef poly (rare).
// NOTE (NaN post-mortem, still applies): clamp u > -1 is REQUIRED; all-zero
// mantissa bits give u = -1 -> log(0) -> -inf -> NaN through the norm.
// ---------------------------------------------------------------------------
__device__ __forceinline__ floatx2 noise_pair(uint32_t ka0, uint32_t ka1,
                                              uint32_t idx0, uint32_t idx1) {
  uint32_t a0, a1, b0, b1;
  threefry2x32(ka0, ka1, 0u, idx0, a0, a1);
  threefry2x32(ka0, ka1, 0u, idx1, b0, b1);
  const uint32_t bitsA = a0 ^ a1, bitsB = b0 ^ b1;
  floatx2 vf;
  vf.x = __uint_as_float(__builtin_amdgcn_alignbit(0x7Fu, bitsA, 9));  // [1,2)
  vf.y = __uint_as_float(__builtin_amdgcn_alignbit(0x7Fu, bitsB, 9));
  floatx2 u = __builtin_elementwise_fma(vf, (floatx2){2.0f, 2.0f},
                                        (floatx2){-3.0f, -3.0f});
  u = __builtin_elementwise_max(u, (floatx2){-0.99999994f, -0.99999994f});
  floatx2 t = __builtin_elementwise_fma(-u, u, (floatx2){1.0f, 1.0f});
  floatx2 l2;
  l2.x = __log2f(t.x);
  l2.y = __log2f(t.y);
  floatx2 a = __builtin_elementwise_fma(
      l2, (floatx2){-0.69314718f, -0.69314718f}, (floatx2){-2.5f, -2.5f});
  floatx2 p = __builtin_elementwise_fma(
      (floatx2){-0.00417768164f, -0.00417768164f}, a,
      (floatx2){0.246640727f, 0.246640727f});
  p = __builtin_elementwise_fma(p, a, (floatx2){1.50140941f, 1.50140941f});
  if (__builtin_expect(l2.x <= -7.2134752f, 0)) p.x = tail_p(l2.x);
  if (__builtin_expect(l2.y <= -7.2134752f, 0)) p.y = tail_p(l2.y);
  floatx2 uc = u * (floatx2){0.014142135623730951f, 0.014142135623730951f};
  return __builtin_elementwise_fma(p, uc, (floatx2){1.0f, 1.0f});
}

// ---------------------------------------------------------------------------
// Device globals: precomputed per-(rowtile,lane) A fragments (f16) + noise key
// g_afrag[t][16], t = rowtile*64+lane: halfs 0..7 = af0 (k=0..31), 8..15 = af1
// ---------------------------------------------------------------------------
__device__ __align__(16) _Float16 g_afrag[256 * 16];
__device__ uint32_t g_key[2];

// ---------------------------------------------------------------------------
// Setup: fold 3 rotations into one real 64-pt circulant kernel g[64] (fp32,
// double only for twiddles), then emit per-tid MFMA A-fragments + threefry key.
// (validated: A[row][k] = g[(row-k)&63] — convolution, not correlation)
// ---------------------------------------------------------------------------
__global__ void setup_kernel(const float* __restrict__ rx,
                             const float* __restrict__ ry,
                             const float* __restrict__ rz) {
  __shared__ float cre[3][64], cim[3][64];
  __shared__ float Gr[64], Gi[64];
  __shared__ float twc[64], tws[64];
  __shared__ float gs[64];
  const int t = threadIdx.x;  // 256 threads

  if (t < 32) {
    const float* ps[3] = {rx, ry, rz};
    for (int a = 0; a < 3; ++a) {
      float s = 0.0f;
      for (int r = 0; r < 16; ++r) s += ps[a][t * 16 + r];
      float h = 0.5f * s;  // theta[:32] * 0.5
      float ch = cosf(h), sh = sinf(h);
      if (a < 2) {  // rx, ry: repeat(cos(half), 2) -> real diag
        cre[a][2 * t] = ch;     cim[a][2 * t] = 0.0f;
        cre[a][2 * t + 1] = ch; cim[a][2 * t + 1] = 0.0f;
      } else {      // rz: [exp(-ih), exp(+ih)] interleaved
        cre[2][2 * t] = ch;     cim[2][2 * t] = -sh;
        cre[2][2 * t + 1] = ch; cim[2][2 * t + 1] = sh;
      }
    }
  }
  if (t < 64) {
    double ang = (2.0 * 3.14159265358979323846 / 64.0) * (double)t;
    twc[t] = (float)cos(ang);
    tws[t] = (float)sin(ang);
  }
  __syncthreads();

  if (t < 64) {  // Hermitian-symmetrize each spectrum, complex product
    const int k = t, kn = (64 - k) & 63;
    float pr = 1.0f, pi = 0.0f;
    for (int a = 0; a < 3; ++a) {
      float cr = 0.5f * (cre[a][k] + cre[a][kn]);
      float ci = 0.5f * (cim[a][k] - cim[a][kn]);
      float nr = pr * cr - pi * ci;
      float ni = pr * ci + pi * cr;
      pr = nr; pi = ni;
    }
    Gr[k] = pr; Gi[k] = pi;
  }
  __syncthreads();

  if (t < 64) {  // g[m] = Re( ifft(G)[m] )
    const int mi = t;
    float s = 0.0f;
    for (int k = 0; k < 64; ++k) {
      int idx = (k * mi) & 63;
      s = fmaf(Gr[k], twc[idx], s);
      s = fmaf(-Gi[k], tws[idx], s);
    }
    gs[mi] = s * (1.0f / 64.0f);
  }
  __syncthreads();

  {
    const int w = t >> 6, lane = t & 63, quad = lane >> 4, m = lane & 15;
    const int r0 = 16 * w + m - 8 * quad;
#pragma unroll
    for (int j = 0; j < 8; ++j) {
      g_afrag[t * 16 + j]     = (_Float16)gs[(r0 - j) & 63];
      g_afrag[t * 16 + 8 + j] = (_Float16)gs[(r0 - 32 - j) & 63];
    }
  }

  if (t == 0) {
    uint32_t o0, o1;
    threefry2x32(0u, 42u, 0u, 0u, o0, o1);  // ka = split(key(42))[0]
    g_key[0] = o0; g_key[1] = o1;
  }
}

// ---------------------------------------------------------------------------
// Main: per (b,t) row. Y = Gm . X via f16 MFMA (fp32 accum); JAX-exact amp
// noise + L2-normalize directly on MFMA C-layout (col=lane&15, row=quad*4+r).
//
// R5 consolidation (post-mortem of R4): the 2048/2048 split regressed total
// by ~7 us (second launch + tail) and the A/B halves fell below the harness
// fill-buffer dispatches in the top-5 table -> unreadable. Merged back to a
// SINGLE 4096-block dispatch, keeping R4's harness-validated trimmed math.
// vs R3 this is exactly one change: ~13% fewer RNG instructions at identical
// structure. Model under test: VALU-issue-bound with constant ~45% efficiency
// (R0->R2: 10% instr cut -> 8% time cut; R3: +waves -> no change; derived
// VALUBusy ~85% is ~2x-inflated by the gfx94x SIMD-16 formula).
// Read: qmain ~44 us => keep cutting instructions (R6: 4-way interleave);
// qmain ~48 us => structural floor, R6 restructures.
// ---------------------------------------------------------------------------
__global__ __launch_bounds__(512, 6) void qmain(const float* __restrict__ x,
                                                float* __restrict__ out) {
  __shared__ __align__(16) _Float16 Xt[64 * 72];  // [d][q], row stride 72 halfs
  __shared__ float red[8];
  const int tid = threadIdx.x;   // 0..511
  const int row = blockIdx.x;    // 0..4095 = b*T + t
  const int lane = tid & 63;
  const int w = tid >> 6;        // wave id 0..7
  const int wr = w & 3;          // output row tile: q rows 16wr..16wr+15
  const int wc = w >> 2;         // output col half: d cols 32wc..32wc+31
  const int quad = lane >> 4;    // 0..3
  const int m = lane & 15;       // A's m index == D's col index

  const half8* at = (const half8*)g_afrag;
  const int ai = (wr << 6) | lane;
  half8 af0 = at[2 * ai];
  half8 af1 = at[2 * ai + 1];
  const uint32_t ka0 = g_key[0], ka1 = g_key[1];

  // stage row -> Xt (cvt f16 + transpose in registers); v[4] dies here, before
  // any RNG state goes live (R6/R1 lesson: do NOT overlap staging w/ threefry)
  {
    const float* xr = x + (size_t)row * 4096;
    const int d0 = (tid & 31) * 2;   // this thread: d rows d0, d0+1
    const int q0 = (tid >> 5) * 4;   // q columns q0..q0+3
    float2 v[4];
#pragma unroll
    for (int s = 0; s < 4; ++s) v[s] = *(const float2*)(xr + (q0 + s) * 64 + d0);
    union { _Float16 h[4]; uint2 u; } r0, r1;
#pragma unroll
    for (int s = 0; s < 4; ++s) { r0.h[s] = (_Float16)v[s].x; r1.h[s] = (_Float16)v[s].y; }
    *(uint2*)&Xt[d0 * 72 + q0] = r0.u;
    *(uint2*)&Xt[(d0 + 1) * 72 + q0] = r1.u;
  }
  __syncthreads();

  // 4 MFMAs: acc[cc] covers Y[16wr+4quad+r][16*(2wc+cc)+m]
  floatx4 acc[2];
#pragma unroll
  for (int cc = 0; cc < 2; ++cc) {
    const int c = 2 * wc + cc;
    const _Float16* bp = &Xt[(16 * c + m) * 72 + 8 * quad];
    half8 b0 = *(const half8*)bp;          // k = 0..31 slice
    half8 b1 = *(const half8*)(bp + 32);   // k = 32..63 slice
    acc[cc] = (floatx4){0.0f, 0.0f, 0.0f, 0.0f};
    acc[cc] = __builtin_amdgcn_mfma_f32_16x16x32_f16(af0, b0, acc[cc], 0, 0, 0);
    acc[cc] = __builtin_amdgcn_mfma_f32_16x16x32_f16(af1, b1, acc[cc], 0, 0, 0);
  }

  // fused noise (paired cc=0,1) + apply in place + sum of squares
  // element (cc, r): (q, d) = (16wr + 4quad + r, 32wc + 16cc + m)
  const uint32_t idxbase = ((uint32_t)row << 12) +
                           (uint32_t)(((16 * wr + 4 * quad) << 6) + (wc << 5) + m);
  floatx2 ss = {0.0f, 0.0f};
#pragma unroll
  for (int r = 0; r < 4; ++r) {
    const uint32_t i0 = idxbase + (uint32_t)(r * 64);
    floatx2 nm = noise_pair(ka0, ka1, i0, i0 + 16u);
    floatx2 val = nm * (floatx2){acc[0][r], acc[1][r]};
    acc[0][r] = val.x; acc[1][r] = val.y;
    ss = __builtin_elementwise_fma(val, val, ss);
  }
  float ssum = ss.x + ss.y;

  // block reduction of sum of squares (8 waves)
#pragma unroll
  for (int off = 32; off >= 1; off >>= 1) ssum += __shfl_xor(ssum, off, 64);
  if (lane == 0) red[w] = ssum;
  __syncthreads();
  float total = 0.0f;
#pragma unroll
  for (int i = 0; i < 8; ++i) total += red[i];
  const float scale = 1.0f / (sqrtf(total) + 1e-8f);

  // stores: one base + 8 immediate-offset dword stores (|.| folds into v_mul)
  float* ob = out + (size_t)row * 4096 +
              (size_t)(((16 * wr + 4 * quad) << 6) + (wc << 5) + m);
#pragma unroll
  for (int cc = 0; cc < 2; ++cc)
#pragma unroll
    for (int r = 0; r < 4; ++r)
      ob[r * 64 + 16 * cc] = fabsf(acc[cc][r]) * scale;
}

// ---------------------------------------------------------------------------
extern "C" void kernel_launch(void* const* d_in, const int* in_sizes, int n_in,
                              void* d_out, int out_size, void* d_ws, size_t ws_size,
                              hipStream_t stream) {
  const float* x  = (const float*)d_in[0];
  const float* rx = (const float*)d_in[1];
  const float* ry = (const float*)d_in[2];
  const float* rz = (const float*)d_in[3];
  float* out = (float*)d_out;

  setup_kernel<<<1, 256, 0, stream>>>(rx, ry, rz);
  qmain<<<4096, 512, 0, stream>>>(x, out);
}

// Round 6
// 137.895 us; speedup vs baseline: 1.0463x; 1.0060x over previous
//
#include <hip/hip_runtime.h>
#include <stdint.h>

typedef _Float16 half8 __attribute__((ext_vector_type(8)));
typedef float floatx4 __attribute__((ext_vector_type(4)));
typedef float floatx2 __attribute__((ext_vector_type(2)));

// ---------------------------------------------------------------------------
// Threefry-2x32, 20 rounds (JAX-compatible, partitionable variant)
// rotl forced to v_alignbit_b32 via builtin (guaranteed 1 instr/rotate).
// RNG BIT SCHEME IS VALIDATED — DO NOT TOUCH (bits = o0^o1 of (0, idx)).
// ---------------------------------------------------------------------------
__device__ __forceinline__ uint32_t rotl32(uint32_t v, int r) {
  return __builtin_amdgcn_alignbit(v, v, 32 - r);  // (v:v)>>(32-r) == rotl
}

__device__ __forceinline__ void threefry2x32(uint32_t k0, uint32_t k1,
                                             uint32_t x0, uint32_t x1,
                                             uint32_t& o0, uint32_t& o1) {
  uint32_t k2 = k0 ^ k1 ^ 0x1BD11BDAu;
  x0 += k0; x1 += k1;
#define TF_R(r) { x0 += x1; x1 = rotl32(x1, (r)); x1 ^= x0; }
  TF_R(13) TF_R(15) TF_R(26) TF_R(6)   x0 += k1; x1 += k2 + 1u;
  TF_R(17) TF_R(29) TF_R(16) TF_R(24)  x0 += k2; x1 += k0 + 2u;
  TF_R(13) TF_R(15) TF_R(26) TF_R(6)   x0 += k0; x1 += k1 + 3u;
  TF_R(17) TF_R(29) TF_R(16) TF_R(24)  x0 += k1; x1 += k2 + 4u;
  TF_R(13) TF_R(15) TF_R(26) TF_R(6)   x0 += k2; x1 += k0 + 5u;
#undef TF_R
  o0 = x0; o1 = x1;
}

// Tail of erfinv (w >= 5, ~0.34% of elements): full 9-coef Giles poly.
__device__ __forceinline__ float tail_p(float l2) {
  float w = l2 * -0.69314718f;
  float s = sqrtf(w) - 3.0f;
  float p = -0.000200214257f;
  p = fmaf(p, s, 0.000100950558f);
  p = fmaf(p, s, 0.00134934322f);
  p = fmaf(p, s, -0.00367342844f);
  p = fmaf(p, s, 0.00573950773f);
  p = fmaf(p, s, -0.0076224613f);
  p = fmaf(p, s, 0.00943887047f);
  p = fmaf(p, s, 1.00167406f);
  p = fmaf(p, s, 2.83297682f);
  return p;
}

// ---------------------------------------------------------------------------
// Paired noise multipliers nm = 1 + 0.01*sqrt(2)*erfinv(u) for (idx0, idx1).
// Harness-validated R4/R5 at absmax 4.88e-4 (identical to scalar R2/R3):
//  - two elements packed as float2 (the interleaved chains also feed ILP).
//  - central poly 3 coefs; dropped-term err ~0.011 on erfinv -> ~2e-5 on
//    output (budget 4.9e-4, f16-matmul-dominated).
//  - tail branch (w >= 5) recomputes with the full 9-coef poly (rare).
// NOTE (NaN post-mortem, still applies): clamp u > -1 is REQUIRED; all-zero
// mantissa bits give u = -1 -> log(0) -> -inf -> NaN through the norm.
// ---------------------------------------------------------------------------
__device__ __forceinline__ floatx2 noise_pair(uint32_t ka0, uint32_t ka1,
                                              uint32_t idx0, uint32_t idx1) {
  uint32_t a0, a1, b0, b1;
  threefry2x32(ka0, ka1, 0u, idx0, a0, a1);
  threefry2x32(ka0, ka1, 0u, idx1, b0, b1);
  const uint32_t bitsA = a0 ^ a1, bitsB = b0 ^ b1;
  floatx2 vf;
  vf.x = __uint_as_float(__builtin_amdgcn_alignbit(0x7Fu, bitsA, 9));  // [1,2)
  vf.y = __uint_as_float(__builtin_amdgcn_alignbit(0x7Fu, bitsB, 9));
  floatx2 u = __builtin_elementwise_fma(vf, (floatx2){2.0f, 2.0f},
                                        (floatx2){-3.0f, -3.0f});
  u = __builtin_elementwise_max(u, (floatx2){-0.99999994f, -0.99999994f});
  floatx2 t = __builtin_elementwise_fma(-u, u, (floatx2){1.0f, 1.0f});
  floatx2 l2;
  l2.x = __log2f(t.x);
  l2.y = __log2f(t.y);
  floatx2 a = __builtin_elementwise_fma(
      l2, (floatx2){-0.69314718f, -0.69314718f}, (floatx2){-2.5f, -2.5f});
  floatx2 p = __builtin_elementwise_fma(
      (floatx2){-0.00417768164f, -0.00417768164f}, a,
      (floatx2){0.246640727f, 0.246640727f});
  p = __builtin_elementwise_fma(p, a, (floatx2){1.50140941f, 1.50140941f});
  if (__builtin_expect(l2.x <= -7.2134752f, 0)) p.x = tail_p(l2.x);
  if (__builtin_expect(l2.y <= -7.2134752f, 0)) p.y = tail_p(l2.y);
  floatx2 uc = u * (floatx2){0.014142135623730951f, 0.014142135623730951f};
  return __builtin_elementwise_fma(p, uc, (floatx2){1.0f, 1.0f});
}

// ---------------------------------------------------------------------------
// Device globals: precomputed per-(rowtile,lane) A fragments (f16) + noise key
// g_afrag[t][16], t = rowtile*64+lane: halfs 0..7 = af0 (k=0..31), 8..15 = af1
// ---------------------------------------------------------------------------
__device__ __align__(16) _Float16 g_afrag[256 * 16];
__device__ uint32_t g_key[2];

// ---------------------------------------------------------------------------
// Setup: fold 3 rotations into one real 64-pt circulant kernel g[64] (fp32,
// double only for twiddles), then emit per-tid MFMA A-fragments + threefry key.
// (validated: A[row][k] = g[(row-k)&63] — convolution, not correlation)
// ---------------------------------------------------------------------------
__global__ void setup_kernel(const float* __restrict__ rx,
                             const float* __restrict__ ry,
                             const float* __restrict__ rz) {
  __shared__ float cre[3][64], cim[3][64];
  __shared__ float Gr[64], Gi[64];
  __shared__ float twc[64], tws[64];
  __shared__ float gs[64];
  const int t = threadIdx.x;  // 256 threads

  if (t < 32) {
    const float* ps[3] = {rx, ry, rz};
    for (int a = 0; a < 3; ++a) {
      float s = 0.0f;
      for (int r = 0; r < 16; ++r) s += ps[a][t * 16 + r];
      float h = 0.5f * s;  // theta[:32] * 0.5
      float ch = cosf(h), sh = sinf(h);
      if (a < 2) {  // rx, ry: repeat(cos(half), 2) -> real diag
        cre[a][2 * t] = ch;     cim[a][2 * t] = 0.0f;
        cre[a][2 * t + 1] = ch; cim[a][2 * t + 1] = 0.0f;
      } else {      // rz: [exp(-ih), exp(+ih)] interleaved
        cre[2][2 * t] = ch;     cim[2][2 * t] = -sh;
        cre[2][2 * t + 1] = ch; cim[2][2 * t + 1] = sh;
      }
    }
  }
  if (t < 64) {
    double ang = (2.0 * 3.14159265358979323846 / 64.0) * (double)t;
    twc[t] = (float)cos(ang);
    tws[t] = (float)sin(ang);
  }
  __syncthreads();

  if (t < 64) {  // Hermitian-symmetrize each spectrum, complex product
    const int k = t, kn = (64 - k) & 63;
    float pr = 1.0f, pi = 0.0f;
    for (int a = 0; a < 3; ++a) {
      float cr = 0.5f * (cre[a][k] + cre[a][kn]);
      float ci = 0.5f * (cim[a][k] - cim[a][kn]);
      float nr = pr * cr - pi * ci;
      float ni = pr * ci + pi * cr;
      pr = nr; pi = ni;
    }
    Gr[k] = pr; Gi[k] = pi;
  }
  __syncthreads();

  if (t < 64) {  // g[m] = Re( ifft(G)[m] )
    const int mi = t;
    float s = 0.0f;
    for (int k = 0; k < 64; ++k) {
      int idx = (k * mi) & 63;
      s = fmaf(Gr[k], twc[idx], s);
      s = fmaf(-Gi[k], tws[idx], s);
    }
    gs[mi] = s * (1.0f / 64.0f);
  }
  __syncthreads();

  {
    const int w = t >> 6, lane = t & 63, quad = lane >> 4, m = lane & 15;
    const int r0 = 16 * w + m - 8 * quad;
#pragma unroll
    for (int j = 0; j < 8; ++j) {
      g_afrag[t * 16 + j]     = (_Float16)gs[(r0 - j) & 63];
      g_afrag[t * 16 + 8 + j] = (_Float16)gs[(r0 - 32 - j) & 63];
    }
  }

  if (t == 0) {
    uint32_t o0, o1;
    threefry2x32(0u, 42u, 0u, 0u, o0, o1);  // ka = split(key(42))[0]
    g_key[0] = o0; g_key[1] = o1;
  }
}

// ---------------------------------------------------------------------------
// Main: per (b,t) row. Y = Gm . X via f16 MFMA (fp32 accum); JAX-exact amp
// noise + L2-normalize directly on MFMA C-layout (col=lane&15, row=quad*4+r).
//
// R6 = H_L test, full grid, single variable vs R5: the RNG (data-independent)
// is hoisted BEFORE the barrier, computed while the x-row global loads are in
// flight. This is R4's qmainB body (harness-validated for correctness; its
// duration was unreadable due to the top-5 cutoff + split-launch overhead).
// Unlike R1's regressing version, register math fits now: 64-reg baseline +
// v[4](8) + nm[4](8) + threefry temps(~8) ~= 78 < (512,6)=84 cap.
// Read: qmain 41-44 us => H_L confirmed (phase serialization was exposed);
// ~48-50 us => H_A (VALU floor), declare or force packed-f32 next.
// Tripwire: WRITE_SIZE must stay exactly 65536 KB (growth = spill).
// ---------------------------------------------------------------------------
__global__ __launch_bounds__(512, 6) void qmain(const float* __restrict__ x,
                                                float* __restrict__ out) {
  __shared__ __align__(16) _Float16 Xt[64 * 72];  // [d][q], row stride 72 halfs
  __shared__ float red[8];
  const int tid = threadIdx.x;   // 0..511
  const int row = blockIdx.x;    // 0..4095 = b*T + t
  const int lane = tid & 63;
  const int w = tid >> 6;        // wave id 0..7
  const int wr = w & 3;          // output row tile: q rows 16wr..16wr+15
  const int wc = w >> 2;         // output col half: d cols 32wc..32wc+31
  const int quad = lane >> 4;    // 0..3
  const int m = lane & 15;       // A's m index == D's col index

  // phase 0: issue global loads (x row + A fragments), keep in flight
  const float* xr = x + (size_t)row * 4096;
  const int d0 = (tid & 31) * 2;   // this thread: d rows d0, d0+1
  const int q0 = (tid >> 5) * 4;   // q columns q0..q0+3
  float2 v[4];
#pragma unroll
  for (int s = 0; s < 4; ++s) v[s] = *(const float2*)(xr + (q0 + s) * 64 + d0);
  const half8* at = (const half8*)g_afrag;
  const int ai = (wr << 6) | lane;
  half8 af0 = at[2 * ai];
  half8 af1 = at[2 * ai + 1];
  const uint32_t ka0 = g_key[0], ka1 = g_key[1];

  // phase 1: ALL noise multipliers while loads are in flight (data-indep RNG)
  const uint32_t idxbase = ((uint32_t)row << 12) +
                           (uint32_t)(((16 * wr + 4 * quad) << 6) + (wc << 5) + m);
  floatx2 nm[4];
#pragma unroll
  for (int r = 0; r < 4; ++r) {
    const uint32_t i0 = idxbase + (uint32_t)(r * 64);
    nm[r] = noise_pair(ka0, ka1, i0, i0 + 16u);
  }

  // phase 2: cvt + transposed LDS staging (loads completed under phase 1)
  {
    union { _Float16 h[4]; uint2 u; } r0, r1;
#pragma unroll
    for (int s = 0; s < 4; ++s) { r0.h[s] = (_Float16)v[s].x; r1.h[s] = (_Float16)v[s].y; }
    *(uint2*)&Xt[d0 * 72 + q0] = r0.u;
    *(uint2*)&Xt[(d0 + 1) * 72 + q0] = r1.u;
  }
  __syncthreads();

  // 4 MFMAs: acc[cc] covers Y[16wr+4quad+r][16*(2wc+cc)+m]
  floatx4 acc[2];
#pragma unroll
  for (int cc = 0; cc < 2; ++cc) {
    const int c = 2 * wc + cc;
    const _Float16* bp = &Xt[(16 * c + m) * 72 + 8 * quad];
    half8 b0 = *(const half8*)bp;          // k = 0..31 slice
    half8 b1 = *(const half8*)(bp + 32);   // k = 32..63 slice
    acc[cc] = (floatx4){0.0f, 0.0f, 0.0f, 0.0f};
    acc[cc] = __builtin_amdgcn_mfma_f32_16x16x32_f16(af0, b0, acc[cc], 0, 0, 0);
    acc[cc] = __builtin_amdgcn_mfma_f32_16x16x32_f16(af1, b1, acc[cc], 0, 0, 0);
  }

  // apply precomputed noise + sum of squares (in place, no shadow copy)
  // element (cc, r): (q, d) = (16wr + 4quad + r, 32wc + 16cc + m)
  floatx2 ss = {0.0f, 0.0f};
#pragma unroll
  for (int r = 0; r < 4; ++r) {
    floatx2 val = nm[r] * (floatx2){acc[0][r], acc[1][r]};
    acc[0][r] = val.x; acc[1][r] = val.y;
    ss = __builtin_elementwise_fma(val, val, ss);
  }
  float ssum = ss.x + ss.y;

  // block reduction of sum of squares (8 waves)
#pragma unroll
  for (int off = 32; off >= 1; off >>= 1) ssum += __shfl_xor(ssum, off, 64);
  if (lane == 0) red[w] = ssum;
  __syncthreads();
  float total = 0.0f;
#pragma unroll
  for (int i = 0; i < 8; ++i) total += red[i];
  const float scale = 1.0f / (sqrtf(total) + 1e-8f);

  // stores: one base + 8 immediate-offset dword stores (|.| folds into v_mul)
  float* ob = out + (size_t)row * 4096 +
              (size_t)(((16 * wr + 4 * quad) << 6) + (wc << 5) + m);
#pragma unroll
  for (int cc = 0; cc < 2; ++cc)
#pragma unroll
    for (int r = 0; r < 4; ++r)
      ob[r * 64 + 16 * cc] = fabsf(acc[cc][r]) * scale;
}

// ---------------------------------------------------------------------------
extern "C" void kernel_launch(void* const* d_in, const int* in_sizes, int n_in,
                              void* d_out, int out_size, void* d_ws, size_t ws_size,
                              hipStream_t stream) {
  const float* x  = (const float*)d_in[0];
  const float* rx = (const float*)d_in[1];
  const float* ry = (const float*)d_in[2];
  const float* rz = (const float*)d_in[3];
  float* out = (float*)d_out;

  setup_kernel<<<1, 256, 0, stream>>>(rx, ry, rz);
  qmain<<<4096, 512, 0, stream>>>(x, out);
}